// Round 6
// baseline (479.898 us; speedup 1.0000x reference)
//
#include <hip/hip_runtime.h>
#include <hip/hip_bf16.h>
#include <cstdint>

// Problem constants: B=8, L=4096, D=768, Y=2048
#define BB 8
#define LL 4096
#define DD 768
#define YY 2048

typedef unsigned short u16;
typedef __bf16 bf16x8 __attribute__((ext_vector_type(8)));
typedef float f32x4 __attribute__((ext_vector_type(4)));

__device__ __forceinline__ u16 f2bf(float f) {
    uint32_t u = __float_as_uint(f);
    u += 0x7fffu + ((u >> 16) & 1u);   // RNE
    return (u16)(u >> 16);
}

#define GLL(src, dst) \
    __builtin_amdgcn_global_load_lds((const __attribute__((address_space(1))) unsigned int*)(src), \
                                     (__attribute__((address_space(3))) unsigned int*)(dst), 16, 0, 0)

// ---------------- cast U (Y*D = 1,572,864 floats) ----------------
__global__ __launch_bounds__(256) void cast_u_k(const float* __restrict__ U, u16* __restrict__ U16) {
    int i = blockIdx.x * 256 + threadIdx.x;          // one float4 per thread
    float4 v = ((const float4*)U)[i];
    ushort4 h;
    h.x = f2bf(v.x); h.y = f2bf(v.y); h.z = f2bf(v.z); h.w = f2bf(v.w);
    ((ushort4*)U16)[i] = h;
}

// -------- cast x -> x16 (B,L,D) bf16 AND xt (B,D,L) bf16 (transpose) --------
__global__ __launch_bounds__(256) void cast_transpose_x_k(const float* __restrict__ x,
                                                          u16* __restrict__ x16,
                                                          u16* __restrict__ xt) {
    __shared__ u16 tile[64 * 65];
    const int d0 = blockIdx.x * 64;
    const int l0 = blockIdx.y * 64;
    const int b  = blockIdx.z;
    const float* xb = x + (size_t)b * LL * DD;
    u16* x16b = x16 + (size_t)b * LL * DD;
    u16* xtb  = xt  + (size_t)b * DD * LL;
    #pragma unroll
    for (int p = 0; p < 4; ++p) {
        int idx = p * 256 + threadIdx.x;
        int r = idx >> 4, c4 = (idx & 15) * 4;       // r: l-offset, c4: d-offset
        float4 v = *(const float4*)(xb + (size_t)(l0 + r) * DD + d0 + c4);
        ushort4 h;
        h.x = f2bf(v.x); h.y = f2bf(v.y); h.z = f2bf(v.z); h.w = f2bf(v.w);
        *(ushort4*)(x16b + (size_t)(l0 + r) * DD + d0 + c4) = h;
        tile[r * 65 + c4]     = h.x;
        tile[r * 65 + c4 + 1] = h.y;
        tile[r * 65 + c4 + 2] = h.z;
        tile[r * 65 + c4 + 3] = h.w;
    }
    __syncthreads();
    #pragma unroll
    for (int p = 0; p < 4; ++p) {
        int idx = p * 256 + threadIdx.x;
        int r = idx >> 4, c4 = (idx & 15) * 4;       // r: d-offset, c4: l-offset
        ushort4 h;
        h.x = tile[(c4    ) * 65 + r];
        h.y = tile[(c4 + 1) * 65 + r];
        h.z = tile[(c4 + 2) * 65 + r];
        h.w = tile[(c4 + 3) * 65 + r];
        *(ushort4*)(xtb + (size_t)(d0 + r) * LL + l0 + c4) = h;
    }
}

// ---------------- GEMM1: expatt = exp(x . U^T)^T, bf16 out + rowsum atomics ----------------
// m-dim = l (x16 tile staged), n-dim = y (U16 tile staged); BOTH operands double-buffered,
// ONE barrier per K-iter: prefetch for tile k+1 is issued right after the barrier and has
// the whole frag-read+MFMA phase in flight before the next barrier's vmcnt(0) drain.
// Epilogue: reg quad = 4 consecutive l -> coalesced ushort4 stores of exp(att[y][l]);
// rowsum via 2 shfl_xor (qd lanes) + 4 atomics/lane.
// (R4 lesson: never stream fragments per-lane from global — stage coalesced.)
__global__ __launch_bounds__(256) void gemm1_k(const u16* __restrict__ Xg, const u16* __restrict__ Ug,
                                               u16* __restrict__ C, float* __restrict__ rowsum) {
    __shared__ u16 As[2 * 4096];      // x tile: 128 l-rows x 32 k, dbuf (16 KB)
    __shared__ u16 Bs[2 * 4096];      // U tile: 128 y-rows x 32 k, dbuf (16 KB)
    const int id = blockIdx.x;
    const int b = id & 7;
    const int r = id >> 3;
    const int nblk = r & 15;          // y-block; inner: 16 y-blocks share one staged x tile
    const int mblk = r >> 4;          // l-block
    const u16* A = Xg + (size_t)b * LL * DD;
    C += (size_t)b * (size_t)YY * LL;
    rowsum += (size_t)b * YY;
    const int m0 = mblk * 128;        // l
    const int n0 = nblk * 128;        // y
    const int t = threadIdx.x;
    const int lane = t & 63;
    const int wave = t >> 6;
    const int wm = (wave >> 1) * 64;  // l
    const int wn = (wave & 1) * 64;   // y
    const int ln = lane & 15;
    const int qd = lane >> 4;
    const int swz = (qd ^ ((ln >> 1) & 3)) * 8;

    const int kq0 = (t & 3) ^ ((t >> 3) & 3);
    const u16* Ab0 = A + (size_t)(m0 + (t >> 2)) * DD + kq0 * 8;
    const u16* Ab1 = A + (size_t)(m0 + (t >> 2) + 64) * DD + kq0 * 8;
    const u16* Bb0 = Ug + (size_t)(n0 + (t >> 2)) * DD + kq0 * 8;
    const u16* Bb1 = Ug + (size_t)(n0 + (t >> 2) + 64) * DD + kq0 * 8;
    const int c0 = t * 8, c1 = (t + 256) * 8;

    // prologue: stage tile 0 into buf 0
    GLL(Ab0, As + c0); GLL(Ab1, As + c1);
    GLL(Bb0, Bs + c0); GLL(Bb1, Bs + c1);

    f32x4 acc[4][4] = {};
    int cur = 0;
    const int KT = DD / 32;           // 24
    for (int kt = 0; kt < KT; ++kt) {
        __syncthreads();              // drains buf[cur] loads; protects buf[cur^1] from overwrite
        if (kt + 1 < KT) {
            const int k0 = (kt + 1) * 32;
            const int nb = (cur ^ 1) * 4096;
            GLL(Ab0 + k0, As + nb + c0); GLL(Ab1 + k0, As + nb + c1);
            GLL(Bb0 + k0, Bs + nb + c0); GLL(Bb1 + k0, Bs + nb + c1);
        }
        const u16* Ap = As + cur * 4096;
        const u16* Bp = Bs + cur * 4096;
        bf16x8 af[4], bfr[4];
        #pragma unroll
        for (int i = 0; i < 4; ++i) {
            af[i]  = *(const bf16x8*)(Ap + (wm + i * 16 + ln) * 32 + swz);
            bfr[i] = *(const bf16x8*)(Bp + (wn + i * 16 + ln) * 32 + swz);
        }
        #pragma unroll
        for (int i = 0; i < 4; ++i)
            #pragma unroll
            for (int j = 0; j < 4; ++j)
                acc[i][j] = __builtin_amdgcn_mfma_f32_16x16x32_bf16(af[i], bfr[j], acc[i][j], 0, 0, 0);
        cur ^= 1;
    }
    // epilogue: acc[i][j][rr] -> att[y = n0+wn+j*16+ln][l = m0+wm+i*16+qd*4+rr]
    #pragma unroll
    for (int j = 0; j < 4; ++j) {
        const int y = n0 + wn + j * 16 + ln;
        u16* Cy = C + (size_t)y * LL + m0 + wm;
        float rs = 0.f;
        #pragma unroll
        for (int i = 0; i < 4; ++i) {
            float e0 = __expf(acc[i][j][0]), e1 = __expf(acc[i][j][1]);
            float e2 = __expf(acc[i][j][2]), e3 = __expf(acc[i][j][3]);
            rs += (e0 + e1) + (e2 + e3);
            ushort4 h;
            h.x = f2bf(e0); h.y = f2bf(e1); h.z = f2bf(e2); h.w = f2bf(e3);
            *(ushort4*)(Cy + i * 16 + qd * 4) = h;
        }
        rs += __shfl_xor(rs, 16, 64);
        rs += __shfl_xor(rs, 32, 64);
        if (qd == 0) atomicAdd(&rowsum[y], rs);
    }
}

// ---------------- GEMM2: split-K=2, dbuf both operands, fused fw-dot + 1/rowsum ----------
// m_tile = expatt(Y x L-half) . xt(D x L-half)^T ; y[b][row] += (fw-dot) / rowsum[row]
__global__ __launch_bounds__(256) void gemm2_k(const u16* __restrict__ Ag, const u16* __restrict__ Bg,
                                               const float* __restrict__ fw,
                                               const float* __restrict__ rowsum,
                                               float* __restrict__ yout) {
    __shared__ u16 As[2 * 4096];
    __shared__ u16 Bs[2 * 4096];
    const int id = blockIdx.x;
    const int b = id & 7;
    const int r2 = id >> 3;              // 0..191
    const int half = r2 / 96;
    const int rr_ = r2 % 96;
    const int nblk = rr_ % 6;            // d-block; inner: 6 share one att y-tile
    const int yblk = rr_ / 6;
    const int ktOff = half * 64;
    const u16* A = Ag + (size_t)b * (size_t)YY * LL;
    const u16* Bx = Bg + (size_t)b * (size_t)DD * LL;
    rowsum += (size_t)b * YY;
    const int m0 = yblk * 128;           // y
    const int n0 = nblk * 128;           // d
    const int t = threadIdx.x;
    const int lane = t & 63;
    const int wave = t >> 6;
    const int wm = (wave >> 1) * 64;
    const int wn = (wave & 1) * 64;
    const int ln = lane & 15;
    const int qd = lane >> 4;
    const int swz = (qd ^ ((ln >> 1) & 3)) * 8;

    const int kq0 = (t & 3) ^ ((t >> 3) & 3);
    const u16* Ab0 = A + (size_t)(m0 + (t >> 2)) * LL + kq0 * 8;
    const u16* Ab1 = A + (size_t)(m0 + (t >> 2) + 64) * LL + kq0 * 8;
    const u16* Bb0 = Bx + (size_t)(n0 + (t >> 2)) * LL + kq0 * 8;
    const u16* Bb1 = Bx + (size_t)(n0 + (t >> 2) + 64) * LL + kq0 * 8;
    const int c0 = t * 8, c1 = (t + 256) * 8;

    {
        const int k0 = ktOff * 32;
        GLL(Ab0 + k0, As + c0); GLL(Ab1 + k0, As + c1);
        GLL(Bb0 + k0, Bs + c0); GLL(Bb1 + k0, Bs + c1);
    }

    f32x4 acc[4][4] = {};
    int cur = 0;
    for (int kt = ktOff; kt < ktOff + 64; ++kt) {
        __syncthreads();
        if (kt + 1 < ktOff + 64) {
            const int k0 = (kt + 1) * 32;
            const int nb = (cur ^ 1) * 4096;
            GLL(Ab0 + k0, As + nb + c0); GLL(Ab1 + k0, As + nb + c1);
            GLL(Bb0 + k0, Bs + nb + c0); GLL(Bb1 + k0, Bs + nb + c1);
        }
        const u16* Ap = As + cur * 4096;
        const u16* Bp = Bs + cur * 4096;
        bf16x8 af[4], bfr[4];
        #pragma unroll
        for (int i = 0; i < 4; ++i) {
            af[i]  = *(const bf16x8*)(Ap + (wm + i * 16 + ln) * 32 + swz);
            bfr[i] = *(const bf16x8*)(Bp + (wn + i * 16 + ln) * 32 + swz);
        }
        #pragma unroll
        for (int i = 0; i < 4; ++i)
            #pragma unroll
            for (int j = 0; j < 4; ++j)
                acc[i][j] = __builtin_amdgcn_mfma_f32_16x16x32_bf16(af[i], bfr[j], acc[i][j], 0, 0, 0);
        cur ^= 1;
    }
    // Fused epilogue: per-row partial dot with fw over this block's 128 d-cols, / rowsum.
    #pragma unroll
    for (int i = 0; i < 4; ++i) {
        #pragma unroll
        for (int rr = 0; rr < 4; ++rr) {
            const int row = m0 + wm + i * 16 + qd * 4 + rr;
            const float* fwr = fw + (size_t)row * DD + n0 + wn;
            float s = acc[i][0][rr] * fwr[ln]
                    + acc[i][1][rr] * fwr[16 + ln]
                    + acc[i][2][rr] * fwr[32 + ln]
                    + acc[i][3][rr] * fwr[48 + ln];
            #pragma unroll
            for (int off = 1; off < 16; off <<= 1) s += __shfl_xor(s, off, 64);
            if (ln == 0) atomicAdd(&yout[(size_t)b * YY + row], s * (1.0f / rowsum[row]));
        }
    }
}

// -------- finalize: y += bias (writeback), CE loss = mean_b( lse(y[b]) - y[b][tgt[b]] ) --------
__global__ __launch_bounds__(256) void ce_loss_k(float* __restrict__ yv,
                                                 const float* __restrict__ fb,
                                                 const int* __restrict__ tgt,
                                                 float* __restrict__ out0) {
    __shared__ float part[8];
    const int t = threadIdx.x;
    const int wave = t >> 6, lane = t & 63;
    #pragma unroll
    for (int rep = 0; rep < 2; ++rep) {
        const int b = wave + rep * 4;
        float* row = yv + b * YY;
        const int tg = tgt[b];
        float v[32];
        float mx = -3.0e38f;
        #pragma unroll
        for (int i = 0; i < 32; ++i) {
            v[i] = row[lane + 64 * i] + fb[lane + 64 * i];
            mx = fmaxf(mx, v[i]);
        }
        float tv = 0.f;
        #pragma unroll
        for (int i = 0; i < 32; ++i) {
            if (lane + 64 * i == tg) tv = v[i];
            row[lane + 64 * i] = v[i];          // write back biased y
        }
        for (int o = 32; o; o >>= 1) mx = fmaxf(mx, __shfl_down(mx, o, 64));
        mx = __shfl(mx, 0, 64);
        float s = 0.f;
        #pragma unroll
        for (int i = 0; i < 32; ++i) s += __expf(v[i] - mx);
        for (int o = 32; o; o >>= 1) { s += __shfl_down(s, o, 64); tv += __shfl_down(tv, o, 64); }
        if (lane == 0) part[b] = mx + logf(s) - tv;
    }
    __syncthreads();
    if (t == 0) {
        float tot = 0.f;
        #pragma unroll
        for (int i = 0; i < 8; ++i) tot += part[i];
        out0[0] = tot * 0.125f;
    }
}

extern "C" void kernel_launch(void* const* d_in, const int* in_sizes, int n_in,
                              void* d_out, int out_size, void* d_ws, size_t ws_size,
                              hipStream_t stream) {
    const float* x   = (const float*)d_in[0];   // (B,L,D)
    const float* Uw  = (const float*)d_in[1];   // (Y,D)
    const float* fw  = (const float*)d_in[2];   // (Y,D)
    const float* fb  = (const float*)d_in[3];   // (Y,)
    const int*   tgt = (const int*)d_in[4];     // (B,)
    float* out = (float*)d_out;                 // [loss, y(B*Y)]

    char* ws = (char*)d_ws;
    u16*  x16  = (u16*)(ws);                          // B*L*D bf16   = 50,331,648 B
    u16*  xt   = (u16*)(ws + 50331648);               // B*D*L bf16   = 50,331,648 B
    u16*  U16  = (u16*)(ws + 100663296);              // Y*D bf16     =  3,145,728 B
    u16*  att  = (u16*)(ws + 103809024);              // B*Y*L bf16   = 134,217,728 B
    float* rowsum = (float*)(ws + 238026752);         // B*Y fp32     = 65,536 B

    hipMemsetAsync(out + 1, 0, (size_t)BB * YY * sizeof(float), stream);  // y accumulator
    hipMemsetAsync(rowsum, 0, (size_t)BB * YY * sizeof(float), stream);   // softmax denom
    cast_u_k<<<1536, 256, 0, stream>>>(Uw, U16);
    cast_transpose_x_k<<<dim3(DD / 64, LL / 64, BB), 256, 0, stream>>>(x, x16, xt);

    // GEMM1: expatt[b](Y x L) = exp(x16[b] . U16^T)^T, + rowsum atomics  [K=768]
    gemm1_k<<<(LL / 128) * (YY / 128) * BB, 256, 0, stream>>>(x16, U16, att, rowsum);

    // GEMM2: split-K=2, dbuf, fused fw-dot + 1/rowsum -> y atomics
    gemm2_k<<<(DD / 128) * (YY / 128) * BB * 2, 256, 0, stream>>>(att, xt, fw, rowsum, out + 1);

    ce_loss_k<<<1, 256, 0, stream>>>(out + 1, fb, tgt, out);
}